// Round 1
// baseline (1253.231 us; speedup 1.0000x reference)
//
#include <hip/hip_runtime.h>
#include <cmath>

constexpr int Bn = 64;    // batch
constexpr int Tn = 128;   // tgt len
constexpr int Sn = 1024;  // src len
constexpr int Dn = 1024;  // model dim

// ---------------------------------------------------------------------------
// Tiled f32 GEMM building blocks: 64x64 output tile, BK=32, 256 threads,
// 4x4 outputs per thread. LDS tiles stored k-major [32][64+4pad] so the inner
// loop is two ds_read_b128 per k (outer-product form), conflict-free/2-way.
// ---------------------------------------------------------------------------

__device__ __forceinline__ void stage_T(const float* __restrict__ G, int ld, int row0, int k0,
                                        float (*Sm)[68], int tid) {
  // G: [rows][ld] row-major, k-contiguous. Stage 64 rows x 32 k transposed
  // into Sm[k][row].
#pragma unroll
  for (int l = 0; l < 2; ++l) {
    const int f = tid + l * 256;
    const int r = f >> 3;           // 0..63 (tile row)
    const int kq = (f & 7) << 2;    // 0,4,...,28
    const float4 v = *reinterpret_cast<const float4*>(G + (size_t)(row0 + r) * ld + (k0 + kq));
    Sm[kq + 0][r] = v.x;
    Sm[kq + 1][r] = v.y;
    Sm[kq + 2][r] = v.z;
    Sm[kq + 3][r] = v.w;
  }
}

__device__ __forceinline__ void stage_N(const float* __restrict__ G, int ld, int k0, int col0,
                                        float (*Sm)[68], int tid) {
  // G: [K][ld] row-major (k rows, n cols). Stage 32 k-rows x 64 cols into
  // Sm[k][col] — no transpose, contiguous float4 stores.
#pragma unroll
  for (int l = 0; l < 2; ++l) {
    const int f = tid + l * 256;
    const int kk = f >> 4;          // 0..31
    const int cq = (f & 15) << 2;   // 0..60
    const float4 v = *reinterpret_cast<const float4*>(G + (size_t)(k0 + kk) * ld + (col0 + cq));
    *reinterpret_cast<float4*>(&Sm[kk][cq]) = v;
  }
}

__device__ __forceinline__ void mma_tile(const float (*As)[68], const float (*Bs)[68],
                                         float acc[4][4], int tx, int ty) {
#pragma unroll
  for (int k = 0; k < 32; ++k) {
    const float4 a = *reinterpret_cast<const float4*>(&As[k][ty * 4]);
    const float4 b = *reinterpret_cast<const float4*>(&Bs[k][tx * 4]);
    const float ar[4] = {a.x, a.y, a.z, a.w};
    const float br[4] = {b.x, b.y, b.z, b.w};
#pragma unroll
    for (int i = 0; i < 4; ++i)
#pragma unroll
      for (int j = 0; j < 4; ++j) acc[i][j] += ar[i] * br[j];
  }
}

// C = A (MxK, row stride ldA) * B^T (B is NxK, row stride ldB); C row stride ldC.
// blockIdx.z = batch; sA/sB/sC are element batch strides.
__global__ void __launch_bounds__(256) gemm_abt_k(const float* __restrict__ A,
                                                  const float* __restrict__ Bm,
                                                  float* __restrict__ C,
                                                  int K, int ldA, int ldB, int ldC,
                                                  size_t sA, size_t sB, size_t sC) {
  __shared__ float As[32][68];
  __shared__ float Bs[32][68];
  const int bz = blockIdx.z;
  A += (size_t)bz * sA; Bm += (size_t)bz * sB; C += (size_t)bz * sC;
  const int tid = threadIdx.x;
  const int tx = tid & 15, ty = tid >> 4;
  const int row0 = blockIdx.y * 64, col0 = blockIdx.x * 64;
  float acc[4][4] = {};
  for (int k0 = 0; k0 < K; k0 += 32) {
    stage_T(A, ldA, row0, k0, As, tid);
    stage_T(Bm, ldB, col0, k0, Bs, tid);
    __syncthreads();
    mma_tile(As, Bs, acc, tx, ty);
    __syncthreads();
  }
#pragma unroll
  for (int i = 0; i < 4; ++i) {
    const float4 v = make_float4(acc[i][0], acc[i][1], acc[i][2], acc[i][3]);
    *reinterpret_cast<float4*>(C + (size_t)(row0 + ty * 4 + i) * ldC + col0 + tx * 4) = v;
  }
}

// C = A (MxK, row stride ldA) * B (KxN, row stride ldB); C row stride ldC.
__global__ void __launch_bounds__(256) gemm_ab_k(const float* __restrict__ A,
                                                 const float* __restrict__ Bm,
                                                 float* __restrict__ C,
                                                 int K, int ldA, int ldB, int ldC,
                                                 size_t sA, size_t sB, size_t sC) {
  __shared__ float As[32][68];
  __shared__ float Bs[32][68];
  const int bz = blockIdx.z;
  A += (size_t)bz * sA; Bm += (size_t)bz * sB; C += (size_t)bz * sC;
  const int tid = threadIdx.x;
  const int tx = tid & 15, ty = tid >> 4;
  const int row0 = blockIdx.y * 64, col0 = blockIdx.x * 64;
  float acc[4][4] = {};
  for (int k0 = 0; k0 < K; k0 += 32) {
    stage_T(A, ldA, row0, k0, As, tid);
    stage_N(Bm, ldB, k0, col0, Bs, tid);
    __syncthreads();
    mma_tile(As, Bs, acc, tx, ty);
    __syncthreads();
  }
#pragma unroll
  for (int i = 0; i < 4; ++i) {
    const float4 v = make_float4(acc[i][0], acc[i][1], acc[i][2], acc[i][3]);
    *reinterpret_cast<float4*>(C + (size_t)(row0 + ty * 4 + i) * ldC + col0 + tx * 4) = v;
  }
}

// attn_h = tanh([c, source] @ W_out^T), written transposed to out0[t][b][d].
// M = B*T (m = b*T + t), N = D, K = 2*D. A operand switches pointer at k=1024.
__global__ void __launch_bounds__(256) attn_out_k(const float* __restrict__ Cc,
                                                  const float* __restrict__ Src,
                                                  const float* __restrict__ Wout,
                                                  float* __restrict__ Out) {
  __shared__ float As[32][68];
  __shared__ float Bs[32][68];
  const int tid = threadIdx.x;
  const int tx = tid & 15, ty = tid >> 4;
  const int row0 = blockIdx.y * 64, col0 = blockIdx.x * 64;
  float acc[4][4] = {};
  for (int k0 = 0; k0 < 2 * Dn; k0 += 32) {
    const float* Aop = (k0 < Dn) ? Cc : Src;
    const int ka = (k0 < Dn) ? k0 : k0 - Dn;
    stage_T(Aop, Dn, row0, ka, As, tid);
    stage_T(Wout, 2 * Dn, col0, k0, Bs, tid);
    __syncthreads();
    mma_tile(As, Bs, acc, tx, ty);
    __syncthreads();
  }
#pragma unroll
  for (int i = 0; i < 4; ++i) {
    const int m = row0 + ty * 4 + i;
    const int b = m >> 7;        // / T (=128)
    const int t = m & 127;       // % T
    const float4 v = make_float4(tanhf(acc[i][0]), tanhf(acc[i][1]),
                                 tanhf(acc[i][2]), tanhf(acc[i][3]));
    *reinterpret_cast<float4*>(Out + ((size_t)t * Bn + b) * Dn + col0 + tx * 4) = v;
  }
}

// ---------------------------------------------------------------------------
// Masked softmax + probs rescale + renormalize. One block per output row
// r = t*B + b of the [T,B,S] layout. Reads align row from av_io (written by
// gemm_abt_k with ldC = B*S), writes norescale to out_nore[r], av back to
// av_io[r] in place (same row: no cross-block hazard).
// ---------------------------------------------------------------------------

__device__ __forceinline__ float block_max(float v, float* red, int tid) {
#pragma unroll
  for (int o = 32; o; o >>= 1) v = fmaxf(v, __shfl_xor(v, o));
  if ((tid & 63) == 0) red[tid >> 6] = v;
  __syncthreads();
  v = fmaxf(fmaxf(red[0], red[1]), fmaxf(red[2], red[3]));
  __syncthreads();
  return v;
}

__device__ __forceinline__ float block_sum(float v, float* red, int tid) {
#pragma unroll
  for (int o = 32; o; o >>= 1) v += __shfl_xor(v, o);
  if ((tid & 63) == 0) red[tid >> 6] = v;
  __syncthreads();
  v = red[0] + red[1] + red[2] + red[3];
  __syncthreads();
  return v;
}

__global__ void __launch_bounds__(256) softmax_k(float* __restrict__ av_io,
                                                 const float* __restrict__ probs,
                                                 const int* __restrict__ lens,
                                                 float* __restrict__ out_nore) {
  __shared__ float red[4];
  const int r = blockIdx.x;        // t*B + b
  const int b = r & (Bn - 1);
  const int tid = threadIdx.x;
  const int len = lens[b];
  float* row = av_io + (size_t)r * Sn;
  const int s0 = tid * 4;

  const float4 x = *reinterpret_cast<const float4*>(row + s0);
  const bool v0 = (s0 + 0) < len, v1 = (s0 + 1) < len, v2 = (s0 + 2) < len, v3 = (s0 + 3) < len;

  float lm = -1e30f;
  if (v0) lm = fmaxf(lm, x.x);
  if (v1) lm = fmaxf(lm, x.y);
  if (v2) lm = fmaxf(lm, x.z);
  if (v3) lm = fmaxf(lm, x.w);
  const float m = block_max(lm, red, tid);

  const float e0 = v0 ? __expf(x.x - m) : 0.f;
  const float e1 = v1 ? __expf(x.y - m) : 0.f;
  const float e2 = v2 ? __expf(x.z - m) : 0.f;
  const float e3 = v3 ? __expf(x.w - m) : 0.f;
  const float esum = block_sum(e0 + e1 + e2 + e3, red, tid);
  const float rs = 1.f / esum;
  const float n0 = e0 * rs, n1 = e1 * rs, n2 = e2 * rs, n3 = e3 * rs;
  *reinterpret_cast<float4*>(out_nore + (size_t)r * Sn + s0) = make_float4(n0, n1, n2, n3);

  const float4 p = *reinterpret_cast<const float4*>(probs + (size_t)b * Sn + s0);
  const float c0 = n0 * p.x, c1 = n1 * p.y, c2 = n2 * p.z, c3 = n3 * p.w;
  const float ssum = block_sum(c0 + c1 + c2 + c3, red, tid);
  const float rss = 1.f / ssum;
  *reinterpret_cast<float4*>(row + s0) = make_float4(c0 * rss, c1 * rss, c2 * rss, c3 * rss);
}

// ---------------------------------------------------------------------------

extern "C" void kernel_launch(void* const* d_in, const int* in_sizes, int n_in,
                              void* d_out, int out_size, void* d_ws, size_t ws_size,
                              hipStream_t stream) {
  const float* src   = (const float*)d_in[0];   // [B,T,D]
  const float* mb    = (const float*)d_in[1];   // [B,S,D]
  const float* probs = (const float*)d_in[2];   // [B,S]
  const int*   lens  = (const int*)d_in[3];     // [B]
  const float* Win   = (const float*)d_in[4];   // [D,D]
  const float* Wout  = (const float*)d_in[5];   // [D,2D]

  float* out  = (float*)d_out;
  float* out0 = out;                              // attn_h      [T,B,D]
  float* out1 = out + (size_t)Tn * Bn * Dn;       // align_vec   [T,B,S]
  float* out2 = out1 + (size_t)Tn * Bn * Sn;      // norescale   [T,B,S]

  float* q = (float*)d_ws;                        // [B,T,D] then reused as c

  // 1) q = source @ W_in^T   (M=B*T, N=D, K=D)
  gemm_abt_k<<<dim3(Dn / 64, (Bn * Tn) / 64, 1), 256, 0, stream>>>(
      src, Win, q, Dn, Dn, Dn, Dn, 0, 0, 0);

  // 2) align[b] = q[b] @ mb[b]^T, stored transposed into out1[t*B+b][s]
  gemm_abt_k<<<dim3(Sn / 64, Tn / 64, Bn), 256, 0, stream>>>(
      q, mb, out1, Dn, Dn, Dn, Bn * Sn,
      (size_t)Tn * Dn, (size_t)Sn * Dn, (size_t)Sn);

  // 3) masked softmax + rescale + renormalize (in place on out1, nore -> out2)
  softmax_k<<<Tn * Bn, 256, 0, stream>>>(out1, probs, lens, out2);

  // 4) c[b] = av[b] @ mb[b]   (av rows live in out1 with row stride B*S)
  gemm_ab_k<<<dim3(Dn / 64, Tn / 64, Bn), 256, 0, stream>>>(
      out1, mb, q, Sn, Bn * Sn, Dn, Dn,
      (size_t)Sn, (size_t)Sn * Dn, (size_t)Tn * Dn);

  // 5) attn_h = tanh([c, src] @ W_out^T) -> out0 transposed
  attn_out_k<<<dim3(Dn / 64, (Bn * Tn) / 64, 1), 256, 0, stream>>>(
      q, src, Wout, out0);
}

// Round 3
// 376.918 us; speedup vs baseline: 3.3249x; 3.3249x over previous
//
#include <hip/hip_runtime.h>
#include <cmath>

constexpr int Bn = 64;    // batch
constexpr int Tn = 128;   // tgt len
constexpr int Sn = 1024;  // src len
constexpr int Dn = 1024;  // model dim

typedef __attribute__((ext_vector_type(8))) _Float16 half8;
typedef __attribute__((ext_vector_type(4))) _Float16 half4;
typedef __attribute__((ext_vector_type(4))) float float4v;

// ---------------------------------------------------------------------------
// fp16 split: x ~= (float)h + (float)l with combined relative error ~2^-23.
// ---------------------------------------------------------------------------
__device__ __forceinline__ void split2(float x, _Float16& h, _Float16& l) {
  h = (_Float16)x;
  l = (_Float16)(x - (float)h);
}

// ---------------------------------------------------------------------------
// LDS staging. Tiles are [128 rows][32 k] stored k-contiguous with row stride
// 40 halves (80 B): banks cycle with period 8 rows -> <=2-way conflict (free).
// ---------------------------------------------------------------------------

// T-layout source (G[rows][ld], k-contiguous), split into hi+lo.
__device__ __forceinline__ void stageT_split(const float* __restrict__ G, size_t ld,
                                             int row0, int k0,
                                             _Float16 (*Sh)[40], _Float16 (*Sl)[40],
                                             int tid) {
#pragma unroll
  for (int it = 0; it < 4; ++it) {
    const int f = tid + it * 256;
    const int r = f >> 3, kq = (f & 7) << 2;
    const float4 v = *reinterpret_cast<const float4*>(G + (size_t)(row0 + r) * ld + k0 + kq);
    _Float16 h0, h1, h2, h3, l0, l1, l2, l3;
    split2(v.x, h0, l0); split2(v.y, h1, l1); split2(v.z, h2, l2); split2(v.w, h3, l3);
    half4 hv = {h0, h1, h2, h3};
    half4 lv = {l0, l1, l2, l3};
    *reinterpret_cast<half4*>(&Sh[r][kq]) = hv;
    *reinterpret_cast<half4*>(&Sl[r][kq]) = lv;
  }
}

// T-layout source, plain fp16 (RNE).
__device__ __forceinline__ void stageT_plain(const float* __restrict__ G, size_t ld,
                                             int row0, int k0,
                                             _Float16 (*Sh)[40], int tid) {
#pragma unroll
  for (int it = 0; it < 4; ++it) {
    const int f = tid + it * 256;
    const int r = f >> 3, kq = (f & 7) << 2;
    const float4 v = *reinterpret_cast<const float4*>(G + (size_t)(row0 + r) * ld + k0 + kq);
    half4 hv = {(_Float16)v.x, (_Float16)v.y, (_Float16)v.z, (_Float16)v.w};
    *reinterpret_cast<half4*>(&Sh[r][kq]) = hv;
  }
}

// Pre-split fp16 source (q from G1) — straight vector copy into LDS.
__device__ __forceinline__ void stageT_h16(const _Float16* __restrict__ Gh,
                                           const _Float16* __restrict__ Gl, size_t ld,
                                           int row0, int k0,
                                           _Float16 (*Sh)[40], _Float16 (*Sl)[40],
                                           int tid) {
#pragma unroll
  for (int it = 0; it < 2; ++it) {
    const int f = tid + it * 256;
    const int r = f >> 2, kq = (f & 3) << 3;
    *reinterpret_cast<half8*>(&Sh[r][kq]) =
        *reinterpret_cast<const half8*>(Gh + (size_t)(row0 + r) * ld + k0 + kq);
    *reinterpret_cast<half8*>(&Sl[r][kq]) =
        *reinterpret_cast<const half8*>(Gl + (size_t)(row0 + r) * ld + k0 + kq);
  }
}

// N-layout source for G4's B (G[K][ld], n-contiguous): stage [32 k][128 n]
// without transpose (row stride 136 halves), plain fp16.
__device__ __forceinline__ void stageN_plain(const float* __restrict__ G, size_t ld,
                                             int k0, int col0,
                                             _Float16 (*Sk)[136], int tid) {
#pragma unroll
  for (int it = 0; it < 4; ++it) {
    const int f = tid + it * 256;
    const int k = f >> 5, n0 = (f & 31) << 2;
    const float4 v = *reinterpret_cast<const float4*>(G + (size_t)(k0 + k) * ld + col0 + n0);
    half4 hv = {(_Float16)v.x, (_Float16)v.y, (_Float16)v.z, (_Float16)v.w};
    *reinterpret_cast<half4*>(&Sk[k][n0]) = hv;
  }
}

// ---------------------------------------------------------------------------
// MFMA cores. Wave w -> 64x64 sub-tile at (wr*64, wc*64); 4x4 frags of
// 16x16x32. Fragment: lane holds row/col = lane&15, 8 contiguous k at
// 8*(lane>>4). C/D: col = lane&15, row = (lane>>4)*4 + i  [m89-verified].
// ---------------------------------------------------------------------------

// A split x B split (drops l*l term): err ~2^-22 per product.
__device__ __forceinline__ void mma_split3(const _Float16 (*Ah)[40], const _Float16 (*Al)[40],
                                           const _Float16 (*Bh)[40], const _Float16 (*Bl)[40],
                                           float4v acc[4][4], int lane, int wr, int wc) {
  const int g = lane >> 4, rr = lane & 15, kb = g << 3;
  half8 ah[4], al[4];
#pragma unroll
  for (int m = 0; m < 4; ++m) {
    ah[m] = *reinterpret_cast<const half8*>(&Ah[wr * 64 + m * 16 + rr][kb]);
    al[m] = *reinterpret_cast<const half8*>(&Al[wr * 64 + m * 16 + rr][kb]);
  }
#pragma unroll
  for (int n = 0; n < 4; ++n) {
    const half8 bh = *reinterpret_cast<const half8*>(&Bh[wc * 64 + n * 16 + rr][kb]);
    const half8 bl = *reinterpret_cast<const half8*>(&Bl[wc * 64 + n * 16 + rr][kb]);
#pragma unroll
    for (int m = 0; m < 4; ++m) {
      acc[m][n] = __builtin_amdgcn_mfma_f32_16x16x32_f16(ah[m], bh, acc[m][n], 0, 0, 0);
      acc[m][n] = __builtin_amdgcn_mfma_f32_16x16x32_f16(al[m], bh, acc[m][n], 0, 0, 0);
      acc[m][n] = __builtin_amdgcn_mfma_f32_16x16x32_f16(ah[m], bl, acc[m][n], 0, 0, 0);
    }
  }
}

// A split x B plain.
__device__ __forceinline__ void mma_split(const _Float16 (*Ah)[40], const _Float16 (*Al)[40],
                                          const _Float16 (*Bh)[40],
                                          float4v acc[4][4], int lane, int wr, int wc) {
  const int g = lane >> 4, rr = lane & 15, kb = g << 3;
  half8 ah[4], al[4];
#pragma unroll
  for (int m = 0; m < 4; ++m) {
    ah[m] = *reinterpret_cast<const half8*>(&Ah[wr * 64 + m * 16 + rr][kb]);
    al[m] = *reinterpret_cast<const half8*>(&Al[wr * 64 + m * 16 + rr][kb]);
  }
#pragma unroll
  for (int n = 0; n < 4; ++n) {
    const half8 b = *reinterpret_cast<const half8*>(&Bh[wc * 64 + n * 16 + rr][kb]);
#pragma unroll
    for (int m = 0; m < 4; ++m) {
      acc[m][n] = __builtin_amdgcn_mfma_f32_16x16x32_f16(ah[m], b, acc[m][n], 0, 0, 0);
      acc[m][n] = __builtin_amdgcn_mfma_f32_16x16x32_f16(al[m], b, acc[m][n], 0, 0, 0);
    }
  }
}

__device__ __forceinline__ void mma_gatherB(const _Float16 (*Ah)[40], const _Float16 (*Bk)[136],
                                            float4v acc[4][4], int lane, int wr, int wc) {
  const int g = lane >> 4, rr = lane & 15, kb = g << 3;
  half8 ah[4];
#pragma unroll
  for (int m = 0; m < 4; ++m)
    ah[m] = *reinterpret_cast<const half8*>(&Ah[wr * 64 + m * 16 + rr][kb]);
#pragma unroll
  for (int n = 0; n < 4; ++n) {
    const int nc = wc * 64 + n * 16 + rr;
    half8 b;
#pragma unroll
    for (int j = 0; j < 8; ++j) b[j] = Bk[kb + j][nc];
#pragma unroll
    for (int m = 0; m < 4; ++m)
      acc[m][n] = __builtin_amdgcn_mfma_f32_16x16x32_f16(ah[m], b, acc[m][n], 0, 0, 0);
  }
}

// ---------------------------------------------------------------------------
// G1: q = source @ W_in^T  (M=8192, N=1024, K=1024), both operands split,
// output pre-split fp16.
// ---------------------------------------------------------------------------
__global__ void __launch_bounds__(256) g1_k(const float* __restrict__ src,
                                            const float* __restrict__ Win,
                                            _Float16* __restrict__ qh,
                                            _Float16* __restrict__ ql) {
  __shared__ _Float16 Ah[128][40], Al[128][40], Bh[128][40], Bl[128][40];
  const int tid = threadIdx.x, lane = tid & 63, w = tid >> 6;
  const int wr = w >> 1, wc = w & 1;
  const int row0 = blockIdx.y * 128, col0 = blockIdx.x * 128;
  float4v acc[4][4] = {};
  for (int k0 = 0; k0 < Dn; k0 += 32) {
    stageT_split(src, Dn, row0, k0, Ah, Al, tid);
    stageT_split(Win, Dn, col0, k0, Bh, Bl, tid);
    __syncthreads();
    mma_split3(Ah, Al, Bh, Bl, acc, lane, wr, wc);
    __syncthreads();
  }
  const int g = lane >> 4, rr = lane & 15;
#pragma unroll
  for (int m = 0; m < 4; ++m)
#pragma unroll
    for (int n = 0; n < 4; ++n)
#pragma unroll
      for (int i = 0; i < 4; ++i) {
        const int row = row0 + wr * 64 + m * 16 + g * 4 + i;
        const int col = col0 + wc * 64 + n * 16 + rr;
        _Float16 h, l; split2(acc[m][n][i], h, l);
        qh[(size_t)row * Dn + col] = h;
        ql[(size_t)row * Dn + col] = l;
      }
}

// ---------------------------------------------------------------------------
// G2: align[b] = q[b] @ mb[b]^T -> out1 laid out [T][B][S] (row stride B*S).
// Both operands split (logits feed a softmax with sigma~32 — needs <1e-3).
// ---------------------------------------------------------------------------
__global__ void __launch_bounds__(256) g2_k(const _Float16* __restrict__ qh,
                                            const _Float16* __restrict__ ql,
                                            const float* __restrict__ mb,
                                            float* __restrict__ out1) {
  __shared__ _Float16 Ah[128][40], Al[128][40], Bh[128][40], Bl[128][40];
  const int tid = threadIdx.x, lane = tid & 63, w = tid >> 6;
  const int wr = w >> 1, wc = w & 1;
  const int b = blockIdx.z, col0 = blockIdx.x * 128;
  const _Float16* qhb = qh + (size_t)b * Tn * Dn;
  const _Float16* qlb = ql + (size_t)b * Tn * Dn;
  const float* mbb = mb + (size_t)b * Sn * Dn;
  float* Cb = out1 + (size_t)b * Sn;
  float4v acc[4][4] = {};
  for (int k0 = 0; k0 < Dn; k0 += 32) {
    stageT_h16(qhb, qlb, Dn, 0, k0, Ah, Al, tid);
    stageT_split(mbb, Dn, col0, k0, Bh, Bl, tid);
    __syncthreads();
    mma_split3(Ah, Al, Bh, Bl, acc, lane, wr, wc);
    __syncthreads();
  }
  const int g = lane >> 4, rr = lane & 15;
#pragma unroll
  for (int m = 0; m < 4; ++m)
#pragma unroll
    for (int n = 0; n < 4; ++n)
#pragma unroll
      for (int i = 0; i < 4; ++i) {
        const int t = wr * 64 + m * 16 + g * 4 + i;       // M=128 tile covers all T
        const int s = col0 + wc * 64 + n * 16 + rr;
        Cb[(size_t)t * (Bn * Sn) + s] = acc[m][n][i];
      }
}

// ---------------------------------------------------------------------------
// Softmax + probs rescale + renorm (in place on out1 rows; nore -> out2).
// ---------------------------------------------------------------------------
__device__ __forceinline__ float block_max(float v, float* red, int tid) {
#pragma unroll
  for (int o = 32; o; o >>= 1) v = fmaxf(v, __shfl_xor(v, o));
  if ((tid & 63) == 0) red[tid >> 6] = v;
  __syncthreads();
  v = fmaxf(fmaxf(red[0], red[1]), fmaxf(red[2], red[3]));
  __syncthreads();
  return v;
}

__device__ __forceinline__ float block_sum(float v, float* red, int tid) {
#pragma unroll
  for (int o = 32; o; o >>= 1) v += __shfl_xor(v, o);
  if ((tid & 63) == 0) red[tid >> 6] = v;
  __syncthreads();
  v = red[0] + red[1] + red[2] + red[3];
  __syncthreads();
  return v;
}

__global__ void __launch_bounds__(256) softmax_k(float* __restrict__ av_io,
                                                 const float* __restrict__ probs,
                                                 const int* __restrict__ lens,
                                                 float* __restrict__ out_nore) {
  __shared__ float red[4];
  const int r = blockIdx.x;        // t*B + b
  const int b = r & (Bn - 1);
  const int tid = threadIdx.x;
  const int len = lens[b];
  float* row = av_io + (size_t)r * Sn;
  const int s0 = tid * 4;

  const float4 x = *reinterpret_cast<const float4*>(row + s0);
  const bool v0 = (s0 + 0) < len, v1 = (s0 + 1) < len, v2 = (s0 + 2) < len, v3 = (s0 + 3) < len;

  float lm = -1e30f;
  if (v0) lm = fmaxf(lm, x.x);
  if (v1) lm = fmaxf(lm, x.y);
  if (v2) lm = fmaxf(lm, x.z);
  if (v3) lm = fmaxf(lm, x.w);
  const float m = block_max(lm, red, tid);

  const float e0 = v0 ? __expf(x.x - m) : 0.f;
  const float e1 = v1 ? __expf(x.y - m) : 0.f;
  const float e2 = v2 ? __expf(x.z - m) : 0.f;
  const float e3 = v3 ? __expf(x.w - m) : 0.f;
  const float esum = block_sum(e0 + e1 + e2 + e3, red, tid);
  const float rs = 1.f / esum;
  const float n0 = e0 * rs, n1 = e1 * rs, n2 = e2 * rs, n3 = e3 * rs;
  *reinterpret_cast<float4*>(out_nore + (size_t)r * Sn + s0) = make_float4(n0, n1, n2, n3);

  const float4 p = *reinterpret_cast<const float4*>(probs + (size_t)b * Sn + s0);
  const float c0 = n0 * p.x, c1 = n1 * p.y, c2 = n2 * p.z, c3 = n3 * p.w;
  const float ssum = block_sum(c0 + c1 + c2 + c3, red, tid);
  const float rss = 1.f / ssum;
  *reinterpret_cast<float4*>(row + s0) = make_float4(c0 * rss, c1 * rss, c2 * rss, c3 * rss);
}

// ---------------------------------------------------------------------------
// G4: c[b] = av[b] @ mb[b]   (av rows in out1 with stride B*S; B staged [k][n]
// with per-lane u16 gather for the fragment). Plain fp16 suffices here:
// av in [0,1] sums to 1, err contribution to attn_h ~1e-3.
// ---------------------------------------------------------------------------
__global__ void __launch_bounds__(256) g4_k(const float* __restrict__ av,
                                            const float* __restrict__ mb,
                                            float* __restrict__ c) {
  __shared__ _Float16 Ah[128][40];
  __shared__ _Float16 Bk[32][136];
  const int tid = threadIdx.x, lane = tid & 63, w = tid >> 6;
  const int wr = w >> 1, wc = w & 1;
  const int b = blockIdx.z, col0 = blockIdx.x * 128;
  const float* avb = av + (size_t)b * Sn;          // row stride Bn*Sn
  const float* mbb = mb + (size_t)b * Sn * Dn;
  float* cb = c + (size_t)b * Tn * Dn;
  float4v acc[4][4] = {};
  for (int k0 = 0; k0 < Sn; k0 += 32) {
    stageT_plain(avb, (size_t)Bn * Sn, 0, k0, Ah, tid);
    stageN_plain(mbb, Dn, k0, col0, Bk, tid);
    __syncthreads();
    mma_gatherB(Ah, Bk, acc, lane, wr, wc);
    __syncthreads();
  }
  const int g = lane >> 4, rr = lane & 15;
#pragma unroll
  for (int m = 0; m < 4; ++m)
#pragma unroll
    for (int n = 0; n < 4; ++n)
#pragma unroll
      for (int i = 0; i < 4; ++i) {
        const int t = wr * 64 + m * 16 + g * 4 + i;
        const int d = col0 + wc * 64 + n * 16 + rr;
        cb[(size_t)t * Dn + d] = acc[m][n][i];
      }
}

// ---------------------------------------------------------------------------
// G5: attn_h = tanh([c, src] @ W_out^T) -> out0 stored [T][B][D].
// A split, B plain (W_out err contributes ~1e-3 max pre-tanh).
// ---------------------------------------------------------------------------
__global__ void __launch_bounds__(256) g5_k(const float* __restrict__ c,
                                            const float* __restrict__ src,
                                            const float* __restrict__ Wout,
                                            float* __restrict__ out0) {
  __shared__ _Float16 Ah[128][40], Al[128][40], Bh[128][40];
  const int tid = threadIdx.x, lane = tid & 63, w = tid >> 6;
  const int wr = w >> 1, wc = w & 1;
  const int row0 = blockIdx.y * 128, col0 = blockIdx.x * 128;
  float4v acc[4][4] = {};
  for (int k0 = 0; k0 < 2 * Dn; k0 += 32) {
    const float* Aop = (k0 < Dn) ? c : src;
    const int ka = k0 & (Dn - 1);
    stageT_split(Aop, Dn, row0, ka, Ah, Al, tid);
    stageT_plain(Wout, 2 * Dn, col0, k0, Bh, tid);
    __syncthreads();
    mma_split(Ah, Al, Bh, acc, lane, wr, wc);
    __syncthreads();
  }
  const int g = lane >> 4, rr = lane & 15;
#pragma unroll
  for (int m = 0; m < 4; ++m)
#pragma unroll
    for (int n = 0; n < 4; ++n)
#pragma unroll
      for (int i = 0; i < 4; ++i) {
        const int mm = row0 + wr * 64 + m * 16 + g * 4 + i;
        const int bb = mm >> 7;          // / T
        const int t = mm & 127;          // % T
        const int d = col0 + wc * 64 + n * 16 + rr;
        out0[((size_t)t * Bn + bb) * Dn + d] = tanhf(acc[m][n][i]);
      }
}

// ---------------------------------------------------------------------------

extern "C" void kernel_launch(void* const* d_in, const int* in_sizes, int n_in,
                              void* d_out, int out_size, void* d_ws, size_t ws_size,
                              hipStream_t stream) {
  const float* src   = (const float*)d_in[0];   // [B,T,D]
  const float* mb    = (const float*)d_in[1];   // [B,S,D]
  const float* probs = (const float*)d_in[2];   // [B,S]
  const int*   lens  = (const int*)d_in[3];     // [B]
  const float* Win   = (const float*)d_in[4];   // [D,D]
  const float* Wout  = (const float*)d_in[5];   // [D,2D]

  float* out  = (float*)d_out;
  float* out0 = out;                              // attn_h      [T,B,D]
  float* out1 = out + (size_t)Tn * Bn * Dn;       // align_vec   [T,B,S]
  float* out2 = out1 + (size_t)Tn * Bn * Sn;      // norescale   [T,B,S]

  // ws: q split (2 x 16.8 MB fp16), later overwritten by c (33.5 MB f32).
  _Float16* qh = (_Float16*)d_ws;
  _Float16* ql = qh + (size_t)Bn * Tn * Dn;
  float* cbuf = (float*)d_ws;

  // 1) q = source @ W_in^T (split fp16 output)
  g1_k<<<dim3(Dn / 128, (Bn * Tn) / 128), 256, 0, stream>>>(src, Win, qh, ql);

  // 2) align[b] = q[b] @ mb[b]^T -> out1 [T][B][S]
  g2_k<<<dim3(Sn / 128, 1, Bn), 256, 0, stream>>>(qh, ql, mb, out1);

  // 3) masked softmax + rescale + renormalize
  softmax_k<<<Tn * Bn, 256, 0, stream>>>(out1, probs, lens, out2);

  // 4) c[b] = av[b] @ mb[b]  (overwrites q region in ws)
  g4_k<<<dim3(Dn / 128, 1, Bn), 256, 0, stream>>>(out1, mb, cbuf);

  // 5) attn_h = tanh([c, src] @ W_out^T) -> out0 [T][B][D]
  g5_k<<<dim3(Dn / 128, (Bn * Tn) / 128), 256, 0, stream>>>(cbuf, src, Wout, out0);
}

// Round 4
// 349.118 us; speedup vs baseline: 3.5897x; 1.0796x over previous
//
#include <hip/hip_runtime.h>
#include <cmath>

constexpr int Bn = 64;    // batch
constexpr int Tn = 128;   // tgt len
constexpr int Sn = 1024;  // src len
constexpr int Dn = 1024;  // model dim

typedef __attribute__((ext_vector_type(8))) _Float16 half8;
typedef __attribute__((ext_vector_type(4))) _Float16 half4;
typedef __attribute__((ext_vector_type(4))) float float4v;

// ---------------------------------------------------------------------------
// fp16 split: x ~= (float)h + (float)l with combined relative error ~2^-23.
// ---------------------------------------------------------------------------
__device__ __forceinline__ void split2(float x, _Float16& h, _Float16& l) {
  h = (_Float16)x;
  l = (_Float16)(x - (float)h);
}

// ---------------------------------------------------------------------------
// LDS staging. Tiles [rows][32 k], k-contiguous, row stride 40 halves (80 B).
// ---------------------------------------------------------------------------

// 128-row T-layout source, split into hi+lo.
__device__ __forceinline__ void stageT_split(const float* __restrict__ G, size_t ld,
                                             int row0, int k0,
                                             _Float16 (*Sh)[40], _Float16 (*Sl)[40],
                                             int tid) {
#pragma unroll
  for (int it = 0; it < 4; ++it) {
    const int f = tid + it * 256;
    const int r = f >> 3, kq = (f & 7) << 2;
    const float4 v = *reinterpret_cast<const float4*>(G + (size_t)(row0 + r) * ld + k0 + kq);
    _Float16 h0, h1, h2, h3, l0, l1, l2, l3;
    split2(v.x, h0, l0); split2(v.y, h1, l1); split2(v.z, h2, l2); split2(v.w, h3, l3);
    half4 hv = {h0, h1, h2, h3};
    half4 lv = {l0, l1, l2, l3};
    *reinterpret_cast<half4*>(&Sh[r][kq]) = hv;
    *reinterpret_cast<half4*>(&Sl[r][kq]) = lv;
  }
}

// 64-row T-layout source, split into hi+lo.
__device__ __forceinline__ void stageT_split64(const float* __restrict__ G, size_t ld,
                                               int row0, int k0,
                                               _Float16 (*Sh)[40], _Float16 (*Sl)[40],
                                               int tid) {
#pragma unroll
  for (int it = 0; it < 2; ++it) {
    const int f = tid + it * 256;
    const int r = f >> 3, kq = (f & 7) << 2;
    const float4 v = *reinterpret_cast<const float4*>(G + (size_t)(row0 + r) * ld + k0 + kq);
    _Float16 h0, h1, h2, h3, l0, l1, l2, l3;
    split2(v.x, h0, l0); split2(v.y, h1, l1); split2(v.z, h2, l2); split2(v.w, h3, l3);
    half4 hv = {h0, h1, h2, h3};
    half4 lv = {l0, l1, l2, l3};
    *reinterpret_cast<half4*>(&Sh[r][kq]) = hv;
    *reinterpret_cast<half4*>(&Sl[r][kq]) = lv;
  }
}

// 128-row T-layout source, plain fp16.
__device__ __forceinline__ void stageT_plain(const float* __restrict__ G, size_t ld,
                                             int row0, int k0,
                                             _Float16 (*Sh)[40], int tid) {
#pragma unroll
  for (int it = 0; it < 4; ++it) {
    const int f = tid + it * 256;
    const int r = f >> 3, kq = (f & 7) << 2;
    const float4 v = *reinterpret_cast<const float4*>(G + (size_t)(row0 + r) * ld + k0 + kq);
    half4 hv = {(_Float16)v.x, (_Float16)v.y, (_Float16)v.z, (_Float16)v.w};
    *reinterpret_cast<half4*>(&Sh[r][kq]) = hv;
  }
}

// Pre-split fp16 source (q from G1) — straight vector copy into LDS.
__device__ __forceinline__ void stageT_h16(const _Float16* __restrict__ Gh,
                                           const _Float16* __restrict__ Gl, size_t ld,
                                           int row0, int k0,
                                           _Float16 (*Sh)[40], _Float16 (*Sl)[40],
                                           int tid) {
#pragma unroll
  for (int it = 0; it < 2; ++it) {
    const int f = tid + it * 256;
    const int r = f >> 2, kq = (f & 3) << 3;
    *reinterpret_cast<half8*>(&Sh[r][kq]) =
        *reinterpret_cast<const half8*>(Gh + (size_t)(row0 + r) * ld + k0 + kq);
    *reinterpret_cast<half8*>(&Sl[r][kq]) =
        *reinterpret_cast<const half8*>(Gl + (size_t)(row0 + r) * ld + k0 + kq);
  }
}

// N-layout source for G4's B (G[K][ld], n-contiguous): stage [32 k][128 n].
__device__ __forceinline__ void stageN_plain(const float* __restrict__ G, size_t ld,
                                             int k0, int col0,
                                             _Float16 (*Sk)[136], int tid) {
#pragma unroll
  for (int it = 0; it < 4; ++it) {
    const int f = tid + it * 256;
    const int k = f >> 5, n0 = (f & 31) << 2;
    const float4 v = *reinterpret_cast<const float4*>(G + (size_t)(k0 + k) * ld + col0 + n0);
    half4 hv = {(_Float16)v.x, (_Float16)v.y, (_Float16)v.z, (_Float16)v.w};
    *reinterpret_cast<half4*>(&Sk[k][n0]) = hv;
  }
}

// ---------------------------------------------------------------------------
// MFMA cores, 16x16x32. Input frag: row/col = lane&15, k = 8*(lane>>4)+[0..7].
// C/D: col = lane&15, row = (lane>>4)*4 + i  [m89-verified].
// ---------------------------------------------------------------------------

// 128x128 tile, 4 waves 2x2 (wr, wc in {0,1}), A split x B split, 3 terms.
__device__ __forceinline__ void mma_split3(const _Float16 (*Ah)[40], const _Float16 (*Al)[40],
                                           const _Float16 (*Bh)[40], const _Float16 (*Bl)[40],
                                           float4v acc[4][4], int lane, int wr, int wc) {
  const int g = lane >> 4, rr = lane & 15, kb = g << 3;
  half8 ah[4], al[4];
#pragma unroll
  for (int m = 0; m < 4; ++m) {
    ah[m] = *reinterpret_cast<const half8*>(&Ah[wr * 64 + m * 16 + rr][kb]);
    al[m] = *reinterpret_cast<const half8*>(&Al[wr * 64 + m * 16 + rr][kb]);
  }
#pragma unroll
  for (int n = 0; n < 4; ++n) {
    const half8 bh = *reinterpret_cast<const half8*>(&Bh[wc * 64 + n * 16 + rr][kb]);
    const half8 bl = *reinterpret_cast<const half8*>(&Bl[wc * 64 + n * 16 + rr][kb]);
#pragma unroll
    for (int m = 0; m < 4; ++m) {
      acc[m][n] = __builtin_amdgcn_mfma_f32_16x16x32_f16(ah[m], bh, acc[m][n], 0, 0, 0);
      acc[m][n] = __builtin_amdgcn_mfma_f32_16x16x32_f16(al[m], bh, acc[m][n], 0, 0, 0);
      acc[m][n] = __builtin_amdgcn_mfma_f32_16x16x32_f16(ah[m], bl, acc[m][n], 0, 0, 0);
    }
  }
}

// 64x128 tile, 4 waves 1x4 (wc = wave id), A split x B split, 3 terms.
__device__ __forceinline__ void mma64_split3(const _Float16 (*Ah)[40], const _Float16 (*Al)[40],
                                             const _Float16 (*Bh)[40], const _Float16 (*Bl)[40],
                                             float4v acc[4][2], int lane, int wc) {
  const int g = lane >> 4, rr = lane & 15, kb = g << 3;
  half8 ah[4], al[4];
#pragma unroll
  for (int m = 0; m < 4; ++m) {
    ah[m] = *reinterpret_cast<const half8*>(&Ah[m * 16 + rr][kb]);
    al[m] = *reinterpret_cast<const half8*>(&Al[m * 16 + rr][kb]);
  }
#pragma unroll
  for (int n = 0; n < 2; ++n) {
    const half8 bh = *reinterpret_cast<const half8*>(&Bh[wc * 32 + n * 16 + rr][kb]);
    const half8 bl = *reinterpret_cast<const half8*>(&Bl[wc * 32 + n * 16 + rr][kb]);
#pragma unroll
    for (int m = 0; m < 4; ++m) {
      acc[m][n] = __builtin_amdgcn_mfma_f32_16x16x32_f16(ah[m], bh, acc[m][n], 0, 0, 0);
      acc[m][n] = __builtin_amdgcn_mfma_f32_16x16x32_f16(al[m], bh, acc[m][n], 0, 0, 0);
      acc[m][n] = __builtin_amdgcn_mfma_f32_16x16x32_f16(ah[m], bl, acc[m][n], 0, 0, 0);
    }
  }
}

// 64x128 tile, 4 waves 1x4, A split x B plain, 2 terms.
__device__ __forceinline__ void mma64_split2(const _Float16 (*Ah)[40], const _Float16 (*Al)[40],
                                             const _Float16 (*Bh)[40],
                                             float4v acc[4][2], int lane, int wc) {
  const int g = lane >> 4, rr = lane & 15, kb = g << 3;
  half8 ah[4], al[4];
#pragma unroll
  for (int m = 0; m < 4; ++m) {
    ah[m] = *reinterpret_cast<const half8*>(&Ah[m * 16 + rr][kb]);
    al[m] = *reinterpret_cast<const half8*>(&Al[m * 16 + rr][kb]);
  }
#pragma unroll
  for (int n = 0; n < 2; ++n) {
    const half8 b = *reinterpret_cast<const half8*>(&Bh[wc * 32 + n * 16 + rr][kb]);
#pragma unroll
    for (int m = 0; m < 4; ++m) {
      acc[m][n] = __builtin_amdgcn_mfma_f32_16x16x32_f16(ah[m], b, acc[m][n], 0, 0, 0);
      acc[m][n] = __builtin_amdgcn_mfma_f32_16x16x32_f16(al[m], b, acc[m][n], 0, 0, 0);
    }
  }
}

__device__ __forceinline__ void mma_gatherB(const _Float16 (*Ah)[40], const _Float16 (*Bk)[136],
                                            float4v acc[4][4], int lane, int wr, int wc) {
  const int g = lane >> 4, rr = lane & 15, kb = g << 3;
  half8 ah[4];
#pragma unroll
  for (int m = 0; m < 4; ++m)
    ah[m] = *reinterpret_cast<const half8*>(&Ah[wr * 64 + m * 16 + rr][kb]);
#pragma unroll
  for (int n = 0; n < 4; ++n) {
    const int nc = wc * 64 + n * 16 + rr;
    half8 b;
#pragma unroll
    for (int j = 0; j < 8; ++j) b[j] = Bk[kb + j][nc];
#pragma unroll
    for (int m = 0; m < 4; ++m)
      acc[m][n] = __builtin_amdgcn_mfma_f32_16x16x32_f16(ah[m], b, acc[m][n], 0, 0, 0);
  }
}

// ---------------------------------------------------------------------------
// G1: q = source @ W_in^T  (M=8192, N=1024, K=1024). BM=64, BN=128.
// Grid (8, 128) = 1024 blocks; XCD swizzle: each XCD owns 16 consecutive by.
// ---------------------------------------------------------------------------
__global__ void __launch_bounds__(256) g1_k(const float* __restrict__ src,
                                            const float* __restrict__ Win,
                                            _Float16* __restrict__ qh,
                                            _Float16* __restrict__ ql) {
  __shared__ _Float16 Ah[64][40], Al[64][40], Bh[128][40], Bl[128][40];
  const int tid = threadIdx.x, lane = tid & 63, wc = tid >> 6;
  const int f = blockIdx.y * 8 + blockIdx.x;          // dispatch index
  const int w = (f & 7) * 128 + (f >> 3);             // XCD-contiguous remap
  const int row0 = (w >> 3) * 64, col0 = (w & 7) * 128;
  float4v acc[4][2] = {};
  for (int k0 = 0; k0 < Dn; k0 += 32) {
    stageT_split64(src, Dn, row0, k0, Ah, Al, tid);
    stageT_split(Win, Dn, col0, k0, Bh, Bl, tid);
    __syncthreads();
    mma64_split3(Ah, Al, Bh, Bl, acc, lane, wc);
    __syncthreads();
  }
  const int g = lane >> 4, rr = lane & 15;
#pragma unroll
  for (int m = 0; m < 4; ++m)
#pragma unroll
    for (int n = 0; n < 2; ++n)
#pragma unroll
      for (int i = 0; i < 4; ++i) {
        const int row = row0 + m * 16 + g * 4 + i;
        const int col = col0 + wc * 32 + n * 16 + rr;
        _Float16 h, l; split2(acc[m][n][i], h, l);
        qh[(size_t)row * Dn + col] = h;
        ql[(size_t)row * Dn + col] = l;
      }
}

// ---------------------------------------------------------------------------
// G2: align[b] = q[b] @ mb[b]^T -> out1 [T][B][S]. BM=128 (mb read once).
// Swizzle: each XCD owns 8 consecutive batches.
// ---------------------------------------------------------------------------
__global__ void __launch_bounds__(256) g2_k(const _Float16* __restrict__ qh,
                                            const _Float16* __restrict__ ql,
                                            const float* __restrict__ mb,
                                            float* __restrict__ out1) {
  __shared__ _Float16 Ah[128][40], Al[128][40], Bh[128][40], Bl[128][40];
  const int tid = threadIdx.x, lane = tid & 63, wv = tid >> 6;
  const int wr = wv >> 1, wc = wv & 1;
  const int f = blockIdx.z * 8 + blockIdx.x;
  const int w = (f & 7) * 64 + (f >> 3);
  const int b = w >> 3, col0 = (w & 7) * 128;
  const _Float16* qhb = qh + (size_t)b * Tn * Dn;
  const _Float16* qlb = ql + (size_t)b * Tn * Dn;
  const float* mbb = mb + (size_t)b * Sn * Dn;
  float* Cb = out1 + (size_t)b * Sn;
  float4v acc[4][4] = {};
  for (int k0 = 0; k0 < Dn; k0 += 32) {
    stageT_h16(qhb, qlb, Dn, 0, k0, Ah, Al, tid);
    stageT_split(mbb, Dn, col0, k0, Bh, Bl, tid);
    __syncthreads();
    mma_split3(Ah, Al, Bh, Bl, acc, lane, wr, wc);
    __syncthreads();
  }
  const int g = lane >> 4, rr = lane & 15;
#pragma unroll
  for (int m = 0; m < 4; ++m)
#pragma unroll
    for (int n = 0; n < 4; ++n)
#pragma unroll
      for (int i = 0; i < 4; ++i) {
        const int t = wr * 64 + m * 16 + g * 4 + i;
        const int s = col0 + wc * 64 + n * 16 + rr;
        Cb[(size_t)t * (Bn * Sn) + s] = acc[m][n][i];
      }
}

// ---------------------------------------------------------------------------
// Softmax + probs rescale + renorm (in place on out1 rows; nore -> out2).
// ---------------------------------------------------------------------------
__device__ __forceinline__ float block_max(float v, float* red, int tid) {
#pragma unroll
  for (int o = 32; o; o >>= 1) v = fmaxf(v, __shfl_xor(v, o));
  if ((tid & 63) == 0) red[tid >> 6] = v;
  __syncthreads();
  v = fmaxf(fmaxf(red[0], red[1]), fmaxf(red[2], red[3]));
  __syncthreads();
  return v;
}

__device__ __forceinline__ float block_sum(float v, float* red, int tid) {
#pragma unroll
  for (int o = 32; o; o >>= 1) v += __shfl_xor(v, o);
  if ((tid & 63) == 0) red[tid >> 6] = v;
  __syncthreads();
  v = red[0] + red[1] + red[2] + red[3];
  __syncthreads();
  return v;
}

__global__ void __launch_bounds__(256) softmax_k(float* __restrict__ av_io,
                                                 const float* __restrict__ probs,
                                                 const int* __restrict__ lens,
                                                 float* __restrict__ out_nore) {
  __shared__ float red[4];
  const int r = blockIdx.x;        // t*B + b
  const int b = r & (Bn - 1);
  const int tid = threadIdx.x;
  const int len = lens[b];
  float* row = av_io + (size_t)r * Sn;
  const int s0 = tid * 4;

  const float4 x = *reinterpret_cast<const float4*>(row + s0);
  const bool v0 = (s0 + 0) < len, v1 = (s0 + 1) < len, v2 = (s0 + 2) < len, v3 = (s0 + 3) < len;

  float lm = -1e30f;
  if (v0) lm = fmaxf(lm, x.x);
  if (v1) lm = fmaxf(lm, x.y);
  if (v2) lm = fmaxf(lm, x.z);
  if (v3) lm = fmaxf(lm, x.w);
  const float m = block_max(lm, red, tid);

  const float e0 = v0 ? __expf(x.x - m) : 0.f;
  const float e1 = v1 ? __expf(x.y - m) : 0.f;
  const float e2 = v2 ? __expf(x.z - m) : 0.f;
  const float e3 = v3 ? __expf(x.w - m) : 0.f;
  const float esum = block_sum(e0 + e1 + e2 + e3, red, tid);
  const float rs = 1.f / esum;
  const float n0 = e0 * rs, n1 = e1 * rs, n2 = e2 * rs, n3 = e3 * rs;
  *reinterpret_cast<float4*>(out_nore + (size_t)r * Sn + s0) = make_float4(n0, n1, n2, n3);

  const float4 p = *reinterpret_cast<const float4*>(probs + (size_t)b * Sn + s0);
  const float c0 = n0 * p.x, c1 = n1 * p.y, c2 = n2 * p.z, c3 = n3 * p.w;
  const float ssum = block_sum(c0 + c1 + c2 + c3, red, tid);
  const float rss = 1.f / ssum;
  *reinterpret_cast<float4*>(row + s0) = make_float4(c0 * rss, c1 * rss, c2 * rss, c3 * rss);
}

// ---------------------------------------------------------------------------
// G4: c[b] = av[b] @ mb[b]. BM=128 (mb read once). Swizzle: 8 batches/XCD.
// ---------------------------------------------------------------------------
__global__ void __launch_bounds__(256) g4_k(const float* __restrict__ av,
                                            const float* __restrict__ mb,
                                            float* __restrict__ c) {
  __shared__ _Float16 Ah[128][40];
  __shared__ _Float16 Bk[32][136];
  const int tid = threadIdx.x, lane = tid & 63, wv = tid >> 6;
  const int wr = wv >> 1, wc = wv & 1;
  const int f = blockIdx.z * 8 + blockIdx.x;
  const int w = (f & 7) * 64 + (f >> 3);
  const int b = w >> 3, col0 = (w & 7) * 128;
  const float* avb = av + (size_t)b * Sn;          // row stride Bn*Sn
  const float* mbb = mb + (size_t)b * Sn * Dn;
  float* cb = c + (size_t)b * Tn * Dn;
  float4v acc[4][4] = {};
  for (int k0 = 0; k0 < Sn; k0 += 32) {
    stageT_plain(avb, (size_t)Bn * Sn, 0, k0, Ah, tid);
    stageN_plain(mbb, Dn, k0, col0, Bk, tid);
    __syncthreads();
    mma_gatherB(Ah, Bk, acc, lane, wr, wc);
    __syncthreads();
  }
  const int g = lane >> 4, rr = lane & 15;
#pragma unroll
  for (int m = 0; m < 4; ++m)
#pragma unroll
    for (int n = 0; n < 4; ++n)
#pragma unroll
      for (int i = 0; i < 4; ++i) {
        const int t = wr * 64 + m * 16 + g * 4 + i;
        const int d = col0 + wc * 64 + n * 16 + rr;
        cb[(size_t)t * Dn + d] = acc[m][n][i];
      }
}

// ---------------------------------------------------------------------------
// G5: attn_h = tanh([c, src] @ W_out^T) -> out0 [T][B][D]. BM=64, BN=128.
// ---------------------------------------------------------------------------
__global__ void __launch_bounds__(256) g5_k(const float* __restrict__ c,
                                            const float* __restrict__ src,
                                            const float* __restrict__ Wout,
                                            float* __restrict__ out0) {
  __shared__ _Float16 Ah[64][40], Al[64][40], Bh[128][40];
  const int tid = threadIdx.x, lane = tid & 63, wc = tid >> 6;
  const int f = blockIdx.y * 8 + blockIdx.x;
  const int w = (f & 7) * 128 + (f >> 3);
  const int row0 = (w >> 3) * 64, col0 = (w & 7) * 128;
  float4v acc[4][2] = {};
  for (int k0 = 0; k0 < 2 * Dn; k0 += 32) {
    const float* Aop = (k0 < Dn) ? c : src;
    const int ka = k0 & (Dn - 1);
    stageT_split64(Aop, Dn, row0, ka, Ah, Al, tid);
    stageT_plain(Wout, 2 * Dn, col0, k0, Bh, tid);
    __syncthreads();
    mma64_split2(Ah, Al, Bh, acc, lane, wc);
    __syncthreads();
  }
  const int g = lane >> 4, rr = lane & 15;
#pragma unroll
  for (int m = 0; m < 4; ++m)
#pragma unroll
    for (int n = 0; n < 2; ++n)
#pragma unroll
      for (int i = 0; i < 4; ++i) {
        const int mm = row0 + m * 16 + g * 4 + i;
        const int bb = mm >> 7;          // / T
        const int t = mm & 127;          // % T
        const int d = col0 + wc * 32 + n * 16 + rr;
        out0[((size_t)t * Bn + bb) * Dn + d] = tanhf(acc[m][n][i]);
      }
}

// ---------------------------------------------------------------------------

extern "C" void kernel_launch(void* const* d_in, const int* in_sizes, int n_in,
                              void* d_out, int out_size, void* d_ws, size_t ws_size,
                              hipStream_t stream) {
  const float* src   = (const float*)d_in[0];   // [B,T,D]
  const float* mb    = (const float*)d_in[1];   // [B,S,D]
  const float* probs = (const float*)d_in[2];   // [B,S]
  const int*   lens  = (const int*)d_in[3];     // [B]
  const float* Win   = (const float*)d_in[4];   // [D,D]
  const float* Wout  = (const float*)d_in[5];   // [D,2D]

  float* out  = (float*)d_out;
  float* out0 = out;                              // attn_h      [T,B,D]
  float* out1 = out + (size_t)Tn * Bn * Dn;       // align_vec   [T,B,S]
  float* out2 = out1 + (size_t)Tn * Bn * Sn;      // norescale   [T,B,S]

  // ws: q split (2 x 16.8 MB fp16), later overwritten by c (33.5 MB f32).
  _Float16* qh = (_Float16*)d_ws;
  _Float16* ql = qh + (size_t)Bn * Tn * Dn;
  float* cbuf = (float*)d_ws;

  // 1) q = source @ W_in^T (split fp16 output)
  g1_k<<<dim3(Dn / 128, (Bn * Tn) / 64), 256, 0, stream>>>(src, Win, qh, ql);

  // 2) align[b] = q[b] @ mb[b]^T -> out1 [T][B][S]
  g2_k<<<dim3(Sn / 128, 1, Bn), 256, 0, stream>>>(qh, ql, mb, out1);

  // 3) masked softmax + rescale + renormalize
  softmax_k<<<Tn * Bn, 256, 0, stream>>>(out1, probs, lens, out2);

  // 4) c[b] = av[b] @ mb[b]  (overwrites q region in ws)
  g4_k<<<dim3(Dn / 128, 1, Bn), 256, 0, stream>>>(out1, mb, cbuf);

  // 5) attn_h = tanh([c, src] @ W_out^T) -> out0 [T][B][D]
  g5_k<<<dim3(Dn / 128, (Bn * Tn) / 64), 256, 0, stream>>>(cbuf, src, Wout, out0);
}

// Round 5
// 339.513 us; speedup vs baseline: 3.6913x; 1.0283x over previous
//
#include <hip/hip_runtime.h>
#include <cmath>

constexpr int Bn = 64;    // batch
constexpr int Tn = 128;   // tgt len
constexpr int Sn = 1024;  // src len
constexpr int Dn = 1024;  // model dim

typedef __attribute__((ext_vector_type(8))) _Float16 half8;
typedef __attribute__((ext_vector_type(4))) _Float16 half4;
typedef __attribute__((ext_vector_type(4))) float float4v;

__device__ __forceinline__ void split2(float x, _Float16& h, _Float16& l) {
  h = (_Float16)x;
  l = (_Float16)(x - (float)h);
}

// ---------------------------------------------------------------------------
// LDS staging. [rows][BK] k-contiguous; row stride 40 halves (80 B) for BK=32,
// 72 halves (144 B) for BK=64 — both give 8-row bank periods (conflict-free).
// ---------------------------------------------------------------------------

// 128-row f32 source -> split hi/lo, BK=32.
__device__ __forceinline__ void stageT_split(const float* __restrict__ G, size_t ld,
                                             int row0, int k0,
                                             _Float16 (*Sh)[40], _Float16 (*Sl)[40],
                                             int tid) {
#pragma unroll
  for (int it = 0; it < 4; ++it) {
    const int f = tid + it * 256;
    const int r = f >> 3, kq = (f & 7) << 2;
    const float4 v = *reinterpret_cast<const float4*>(G + (size_t)(row0 + r) * ld + k0 + kq);
    _Float16 h0, h1, h2, h3, l0, l1, l2, l3;
    split2(v.x, h0, l0); split2(v.y, h1, l1); split2(v.z, h2, l2); split2(v.w, h3, l3);
    half4 hv = {h0, h1, h2, h3};
    half4 lv = {l0, l1, l2, l3};
    *reinterpret_cast<half4*>(&Sh[r][kq]) = hv;
    *reinterpret_cast<half4*>(&Sl[r][kq]) = lv;
  }
}

// 64-row f32 source -> split hi/lo, BK=32.
__device__ __forceinline__ void stageT_split64(const float* __restrict__ G, size_t ld,
                                               int row0, int k0,
                                               _Float16 (*Sh)[40], _Float16 (*Sl)[40],
                                               int tid) {
#pragma unroll
  for (int it = 0; it < 2; ++it) {
    const int f = tid + it * 256;
    const int r = f >> 3, kq = (f & 7) << 2;
    const float4 v = *reinterpret_cast<const float4*>(G + (size_t)(row0 + r) * ld + k0 + kq);
    _Float16 h0, h1, h2, h3, l0, l1, l2, l3;
    split2(v.x, h0, l0); split2(v.y, h1, l1); split2(v.z, h2, l2); split2(v.w, h3, l3);
    half4 hv = {h0, h1, h2, h3};
    half4 lv = {l0, l1, l2, l3};
    *reinterpret_cast<half4*>(&Sh[r][kq]) = hv;
    *reinterpret_cast<half4*>(&Sl[r][kq]) = lv;
  }
}

// 128-row f32 source -> plain fp16, BK=32.
__device__ __forceinline__ void stageT_plain(const float* __restrict__ G, size_t ld,
                                             int row0, int k0,
                                             _Float16 (*Sh)[40], int tid) {
#pragma unroll
  for (int it = 0; it < 4; ++it) {
    const int f = tid + it * 256;
    const int r = f >> 3, kq = (f & 7) << 2;
    const float4 v = *reinterpret_cast<const float4*>(G + (size_t)(row0 + r) * ld + k0 + kq);
    half4 hv = {(_Float16)v.x, (_Float16)v.y, (_Float16)v.z, (_Float16)v.w};
    *reinterpret_cast<half4*>(&Sh[r][kq]) = hv;
  }
}

// Pre-split fp16 source (q) -> copy, 128 rows, BK=32.
__device__ __forceinline__ void stageT_h16(const _Float16* __restrict__ Gh,
                                           const _Float16* __restrict__ Gl, size_t ld,
                                           int row0, int k0,
                                           _Float16 (*Sh)[40], _Float16 (*Sl)[40],
                                           int tid) {
#pragma unroll
  for (int it = 0; it < 2; ++it) {
    const int f = tid + it * 256;
    const int r = f >> 2, kq = (f & 3) << 3;
    *reinterpret_cast<half8*>(&Sh[r][kq]) =
        *reinterpret_cast<const half8*>(Gh + (size_t)(row0 + r) * ld + k0 + kq);
    *reinterpret_cast<half8*>(&Sl[r][kq]) =
        *reinterpret_cast<const half8*>(Gl + (size_t)(row0 + r) * ld + k0 + kq);
  }
}

// g5 BK=64 helpers ----------------------------------------------------------

// fp16 source (c), 64 rows x 64 k: pure copy.
__device__ __forceinline__ void stage64x64_h16(const _Float16* __restrict__ G, size_t ld,
                                               int row0, int k0,
                                               _Float16 (*Sh)[72], int tid) {
#pragma unroll
  for (int it = 0; it < 2; ++it) {
    const int f = tid + it * 256;
    const int r = f >> 3, kq = (f & 7) << 3;
    *reinterpret_cast<half8*>(&Sh[r][kq]) =
        *reinterpret_cast<const half8*>(G + (size_t)(row0 + r) * ld + k0 + kq);
  }
}

// f32 source, 64 rows x 64 k -> plain fp16.
__device__ __forceinline__ void stage64x64_f32(const float* __restrict__ G, size_t ld,
                                               int row0, int k0,
                                               _Float16 (*Sh)[72], int tid) {
#pragma unroll
  for (int it = 0; it < 4; ++it) {
    const int f = tid + it * 256;
    const int r = f >> 4, kq = (f & 15) << 2;
    const float4 v = *reinterpret_cast<const float4*>(G + (size_t)(row0 + r) * ld + k0 + kq);
    half4 hv = {(_Float16)v.x, (_Float16)v.y, (_Float16)v.z, (_Float16)v.w};
    *reinterpret_cast<half4*>(&Sh[r][kq]) = hv;
  }
}

// f32 source, 128 rows x 64 k -> plain fp16.
__device__ __forceinline__ void stage128x64_f32(const float* __restrict__ G, size_t ld,
                                                int row0, int k0,
                                                _Float16 (*Sh)[72], int tid) {
#pragma unroll
  for (int it = 0; it < 8; ++it) {
    const int f = tid + it * 256;
    const int r = f >> 4, kq = (f & 15) << 2;
    const float4 v = *reinterpret_cast<const float4*>(G + (size_t)(row0 + r) * ld + k0 + kq);
    half4 hv = {(_Float16)v.x, (_Float16)v.y, (_Float16)v.z, (_Float16)v.w};
    *reinterpret_cast<half4*>(&Sh[r][kq]) = hv;
  }
}

// N-layout source for G4's B: stage [32 k][128 n].
__device__ __forceinline__ void stageN_plain(const float* __restrict__ G, size_t ld,
                                             int k0, int col0,
                                             _Float16 (*Sk)[136], int tid) {
#pragma unroll
  for (int it = 0; it < 4; ++it) {
    const int f = tid + it * 256;
    const int k = f >> 5, n0 = (f & 31) << 2;
    const float4 v = *reinterpret_cast<const float4*>(G + (size_t)(k0 + k) * ld + col0 + n0);
    half4 hv = {(_Float16)v.x, (_Float16)v.y, (_Float16)v.z, (_Float16)v.w};
    *reinterpret_cast<half4*>(&Sk[k][n0]) = hv;
  }
}

// ---------------------------------------------------------------------------
// MFMA cores, 16x16x32. Input frag: row/col = lane&15, k = 8*(lane>>4)+[0..7].
// C/D: col = lane&15, row = (lane>>4)*4 + i  [m89-verified].
// ---------------------------------------------------------------------------

// g1: 64x128 tile, 4 waves 1x4, A split x B split (3 terms).
__device__ __forceinline__ void mma64_split3(const _Float16 (*Ah)[40], const _Float16 (*Al)[40],
                                             const _Float16 (*Bh)[40], const _Float16 (*Bl)[40],
                                             float4v acc[4][2], int lane, int wc) {
  const int g = lane >> 4, rr = lane & 15, kb = g << 3;
  half8 ah[4], al[4];
#pragma unroll
  for (int m = 0; m < 4; ++m) {
    ah[m] = *reinterpret_cast<const half8*>(&Ah[m * 16 + rr][kb]);
    al[m] = *reinterpret_cast<const half8*>(&Al[m * 16 + rr][kb]);
  }
#pragma unroll
  for (int n = 0; n < 2; ++n) {
    const half8 bh = *reinterpret_cast<const half8*>(&Bh[wc * 32 + n * 16 + rr][kb]);
    const half8 bl = *reinterpret_cast<const half8*>(&Bl[wc * 32 + n * 16 + rr][kb]);
#pragma unroll
    for (int m = 0; m < 4; ++m) {
      acc[m][n] = __builtin_amdgcn_mfma_f32_16x16x32_f16(ah[m], bh, acc[m][n], 0, 0, 0);
      acc[m][n] = __builtin_amdgcn_mfma_f32_16x16x32_f16(al[m], bh, acc[m][n], 0, 0, 0);
      acc[m][n] = __builtin_amdgcn_mfma_f32_16x16x32_f16(ah[m], bl, acc[m][n], 0, 0, 0);
    }
  }
}

// g2: 128x64 tile, 4 waves 2x2 (64m x 32n each), A split x B split (3 terms).
__device__ __forceinline__ void mma12864_split3(const _Float16 (*Ah)[40], const _Float16 (*Al)[40],
                                                const _Float16 (*Bh)[40], const _Float16 (*Bl)[40],
                                                float4v acc[4][2], int lane, int wr, int wc) {
  const int g = lane >> 4, rr = lane & 15, kb = g << 3;
  half8 ah[4], al[4];
#pragma unroll
  for (int m = 0; m < 4; ++m) {
    ah[m] = *reinterpret_cast<const half8*>(&Ah[wr * 64 + m * 16 + rr][kb]);
    al[m] = *reinterpret_cast<const half8*>(&Al[wr * 64 + m * 16 + rr][kb]);
  }
#pragma unroll
  for (int n = 0; n < 2; ++n) {
    const half8 bh = *reinterpret_cast<const half8*>(&Bh[wc * 32 + n * 16 + rr][kb]);
    const half8 bl = *reinterpret_cast<const half8*>(&Bl[wc * 32 + n * 16 + rr][kb]);
#pragma unroll
    for (int m = 0; m < 4; ++m) {
      acc[m][n] = __builtin_amdgcn_mfma_f32_16x16x32_f16(ah[m], bh, acc[m][n], 0, 0, 0);
      acc[m][n] = __builtin_amdgcn_mfma_f32_16x16x32_f16(al[m], bh, acc[m][n], 0, 0, 0);
      acc[m][n] = __builtin_amdgcn_mfma_f32_16x16x32_f16(ah[m], bl, acc[m][n], 0, 0, 0);
    }
  }
}

// g5: 64x128 tile, BK=64, 4 waves 1x4, plain (1 term).
__device__ __forceinline__ void mma64_bk64_plain(const _Float16 (*Ah)[72], const _Float16 (*Bh)[72],
                                                 float4v acc[4][2], int lane, int wc) {
  const int g = lane >> 4, rr = lane & 15;
#pragma unroll
  for (int kk = 0; kk < 2; ++kk) {
    const int kb = kk * 32 + (g << 3);
    half8 ah[4];
#pragma unroll
    for (int m = 0; m < 4; ++m)
      ah[m] = *reinterpret_cast<const half8*>(&Ah[m * 16 + rr][kb]);
#pragma unroll
    for (int n = 0; n < 2; ++n) {
      const half8 b = *reinterpret_cast<const half8*>(&Bh[wc * 32 + n * 16 + rr][kb]);
#pragma unroll
      for (int m = 0; m < 4; ++m)
        acc[m][n] = __builtin_amdgcn_mfma_f32_16x16x32_f16(ah[m], b, acc[m][n], 0, 0, 0);
    }
  }
}

// g4: 128x128 tile, 4 waves 2x2, B gathered from [k][n] layout.
__device__ __forceinline__ void mma_gatherB(const _Float16 (*Ah)[40], const _Float16 (*Bk)[136],
                                            float4v acc[4][4], int lane, int wr, int wc) {
  const int g = lane >> 4, rr = lane & 15, kb = g << 3;
  half8 ah[4];
#pragma unroll
  for (int m = 0; m < 4; ++m)
    ah[m] = *reinterpret_cast<const half8*>(&Ah[wr * 64 + m * 16 + rr][kb]);
#pragma unroll
  for (int n = 0; n < 4; ++n) {
    const int nc = wc * 64 + n * 16 + rr;
    half8 b;
#pragma unroll
    for (int j = 0; j < 8; ++j) b[j] = Bk[kb + j][nc];
#pragma unroll
    for (int m = 0; m < 4; ++m)
      acc[m][n] = __builtin_amdgcn_mfma_f32_16x16x32_f16(ah[m], b, acc[m][n], 0, 0, 0);
  }
}

// ---------------------------------------------------------------------------
// G1: q = source @ W_in^T. BM=64, BN=128, split3, 1024 blocks.
// ---------------------------------------------------------------------------
__global__ void __launch_bounds__(256) g1_k(const float* __restrict__ src,
                                            const float* __restrict__ Win,
                                            _Float16* __restrict__ qh,
                                            _Float16* __restrict__ ql) {
  __shared__ _Float16 Ah[64][40], Al[64][40], Bh[128][40], Bl[128][40];
  const int tid = threadIdx.x, lane = tid & 63, wc = tid >> 6;
  const int f = blockIdx.y * 8 + blockIdx.x;
  const int w = (f & 7) * 128 + (f >> 3);          // XCD-contiguous remap
  const int row0 = (w >> 3) * 64, col0 = (w & 7) * 128;
  float4v acc[4][2] = {};
  for (int k0 = 0; k0 < Dn; k0 += 32) {
    stageT_split64(src, Dn, row0, k0, Ah, Al, tid);
    stageT_split(Win, Dn, col0, k0, Bh, Bl, tid);
    __syncthreads();
    mma64_split3(Ah, Al, Bh, Bl, acc, lane, wc);
    __syncthreads();
  }
  const int g = lane >> 4, rr = lane & 15;
#pragma unroll
  for (int m = 0; m < 4; ++m)
#pragma unroll
    for (int n = 0; n < 2; ++n)
#pragma unroll
      for (int i = 0; i < 4; ++i) {
        const int row = row0 + m * 16 + g * 4 + i;
        const int col = col0 + wc * 32 + n * 16 + rr;
        _Float16 h, l; split2(acc[m][n][i], h, l);
        qh[(size_t)row * Dn + col] = h;
        ql[(size_t)row * Dn + col] = l;
      }
}

// ---------------------------------------------------------------------------
// G2: align[b] = q[b] @ mb[b]^T -> out1 [T][B][S]. BM=128, BN=64, split3.
// 1024 blocks; 8 batches per XCD.
// ---------------------------------------------------------------------------
__global__ void __launch_bounds__(256) g2_k(const _Float16* __restrict__ qh,
                                            const _Float16* __restrict__ ql,
                                            const float* __restrict__ mb,
                                            float* __restrict__ out1) {
  __shared__ _Float16 Ah[128][40], Al[128][40], Bh[64][40], Bl[64][40];
  const int tid = threadIdx.x, lane = tid & 63, wv = tid >> 6;
  const int wr = wv >> 1, wc = wv & 1;
  const int id = blockIdx.z * 16 + blockIdx.x;
  const int j = id >> 3;
  const int b = (id & 7) * 8 + (j >> 4), col0 = (j & 15) * 64;
  const _Float16* qhb = qh + (size_t)b * Tn * Dn;
  const _Float16* qlb = ql + (size_t)b * Tn * Dn;
  const float* mbb = mb + (size_t)b * Sn * Dn;
  float* Cb = out1 + (size_t)b * Sn;
  float4v acc[4][2] = {};
  for (int k0 = 0; k0 < Dn; k0 += 32) {
    stageT_h16(qhb, qlb, Dn, 0, k0, Ah, Al, tid);
    stageT_split64(mbb, Dn, col0, k0, Bh, Bl, tid);
    __syncthreads();
    mma12864_split3(Ah, Al, Bh, Bl, acc, lane, wr, wc);
    __syncthreads();
  }
  const int g = lane >> 4, rr = lane & 15;
#pragma unroll
  for (int m = 0; m < 4; ++m)
#pragma unroll
    for (int n = 0; n < 2; ++n)
#pragma unroll
      for (int i = 0; i < 4; ++i) {
        const int t = wr * 64 + m * 16 + g * 4 + i;
        const int s = col0 + wc * 32 + n * 16 + rr;
        Cb[(size_t)t * (Bn * Sn) + s] = acc[m][n][i];
      }
}

// ---------------------------------------------------------------------------
// Softmax + probs rescale + renorm (in place on out1 rows; nore -> out2).
// ---------------------------------------------------------------------------
__device__ __forceinline__ float block_max(float v, float* red, int tid) {
#pragma unroll
  for (int o = 32; o; o >>= 1) v = fmaxf(v, __shfl_xor(v, o));
  if ((tid & 63) == 0) red[tid >> 6] = v;
  __syncthreads();
  v = fmaxf(fmaxf(red[0], red[1]), fmaxf(red[2], red[3]));
  __syncthreads();
  return v;
}

__device__ __forceinline__ float block_sum(float v, float* red, int tid) {
#pragma unroll
  for (int o = 32; o; o >>= 1) v += __shfl_xor(v, o);
  if ((tid & 63) == 0) red[tid >> 6] = v;
  __syncthreads();
  v = red[0] + red[1] + red[2] + red[3];
  __syncthreads();
  return v;
}

__global__ void __launch_bounds__(256) softmax_k(float* __restrict__ av_io,
                                                 const float* __restrict__ probs,
                                                 const int* __restrict__ lens,
                                                 float* __restrict__ out_nore) {
  __shared__ float red[4];
  const int r = blockIdx.x;        // t*B + b
  const int b = r & (Bn - 1);
  const int tid = threadIdx.x;
  const int len = lens[b];
  float* row = av_io + (size_t)r * Sn;
  const int s0 = tid * 4;

  const float4 x = *reinterpret_cast<const float4*>(row + s0);
  const bool v0 = (s0 + 0) < len, v1 = (s0 + 1) < len, v2 = (s0 + 2) < len, v3 = (s0 + 3) < len;

  float lm = -1e30f;
  if (v0) lm = fmaxf(lm, x.x);
  if (v1) lm = fmaxf(lm, x.y);
  if (v2) lm = fmaxf(lm, x.z);
  if (v3) lm = fmaxf(lm, x.w);
  const float m = block_max(lm, red, tid);

  const float e0 = v0 ? __expf(x.x - m) : 0.f;
  const float e1 = v1 ? __expf(x.y - m) : 0.f;
  const float e2 = v2 ? __expf(x.z - m) : 0.f;
  const float e3 = v3 ? __expf(x.w - m) : 0.f;
  const float esum = block_sum(e0 + e1 + e2 + e3, red, tid);
  const float rs = 1.f / esum;
  const float n0 = e0 * rs, n1 = e1 * rs, n2 = e2 * rs, n3 = e3 * rs;
  *reinterpret_cast<float4*>(out_nore + (size_t)r * Sn + s0) = make_float4(n0, n1, n2, n3);

  const float4 p = *reinterpret_cast<const float4*>(probs + (size_t)b * Sn + s0);
  const float c0 = n0 * p.x, c1 = n1 * p.y, c2 = n2 * p.z, c3 = n3 * p.w;
  const float ssum = block_sum(c0 + c1 + c2 + c3, red, tid);
  const float rss = 1.f / ssum;
  *reinterpret_cast<float4*>(row + s0) = make_float4(c0 * rss, c1 * rss, c2 * rss, c3 * rss);
}

// ---------------------------------------------------------------------------
// G4: c[b] = av[b] @ mb[b], c written as fp16. 512 blocks; 8 batches/XCD.
// ---------------------------------------------------------------------------
__global__ void __launch_bounds__(256) g4_k(const float* __restrict__ av,
                                            const float* __restrict__ mb,
                                            _Float16* __restrict__ c) {
  __shared__ _Float16 Ah[128][40];
  __shared__ _Float16 Bk[32][136];
  const int tid = threadIdx.x, lane = tid & 63, wv = tid >> 6;
  const int wr = wv >> 1, wc = wv & 1;
  const int id = blockIdx.z * 8 + blockIdx.x;
  const int j = id >> 3;
  const int b = (id & 7) * 8 + (j >> 3), col0 = (j & 7) * 128;
  const float* avb = av + (size_t)b * Sn;          // row stride Bn*Sn
  const float* mbb = mb + (size_t)b * Sn * Dn;
  _Float16* cb = c + (size_t)b * Tn * Dn;
  float4v acc[4][4] = {};
  for (int k0 = 0; k0 < Sn; k0 += 32) {
    stageT_plain(avb, (size_t)Bn * Sn, 0, k0, Ah, tid);
    stageN_plain(mbb, Dn, k0, col0, Bk, tid);
    __syncthreads();
    mma_gatherB(Ah, Bk, acc, lane, wr, wc);
    __syncthreads();
  }
  const int g = lane >> 4, rr = lane & 15;
#pragma unroll
  for (int m = 0; m < 4; ++m)
#pragma unroll
    for (int n = 0; n < 4; ++n)
#pragma unroll
      for (int i = 0; i < 4; ++i) {
        const int t = wr * 64 + m * 16 + g * 4 + i;
        const int d = col0 + wc * 64 + n * 16 + rr;
        cb[(size_t)t * Dn + d] = (_Float16)acc[m][n][i];
      }
}

// ---------------------------------------------------------------------------
// G5: attn_h = tanh([c, src] @ W_out^T) -> out0 [T][B][D].
// BM=64, BN=128, BK=64, plain fp16 (1 MFMA term). c arrives as fp16.
// ---------------------------------------------------------------------------
__global__ void __launch_bounds__(256) g5_k(const _Float16* __restrict__ c,
                                            const float* __restrict__ src,
                                            const float* __restrict__ Wout,
                                            float* __restrict__ out0) {
  __shared__ _Float16 Ah[64][72], Bh[128][72];
  const int tid = threadIdx.x, lane = tid & 63, wc = tid >> 6;
  const int f = blockIdx.y * 8 + blockIdx.x;
  const int w = (f & 7) * 128 + (f >> 3);
  const int row0 = (w >> 3) * 64, col0 = (w & 7) * 128;
  float4v acc[4][2] = {};
  for (int k0 = 0; k0 < 2 * Dn; k0 += 64) {
    if (k0 < Dn) stage64x64_h16(c, Dn, row0, k0, Ah, tid);
    else         stage64x64_f32(src, Dn, row0, k0 - Dn, Ah, tid);
    stage128x64_f32(Wout, 2 * Dn, col0, k0, Bh, tid);
    __syncthreads();
    mma64_bk64_plain(Ah, Bh, acc, lane, wc);
    __syncthreads();
  }
  const int g = lane >> 4, rr = lane & 15;
#pragma unroll
  for (int m = 0; m < 4; ++m)
#pragma unroll
    for (int n = 0; n < 2; ++n)
#pragma unroll
      for (int i = 0; i < 4; ++i) {
        const int mm = row0 + m * 16 + g * 4 + i;
        const int bb = mm >> 7;          // / T
        const int t = mm & 127;          // % T
        const int d = col0 + wc * 32 + n * 16 + rr;
        out0[((size_t)t * Bn + bb) * Dn + d] = tanhf(acc[m][n][i]);
      }
}

// ---------------------------------------------------------------------------

extern "C" void kernel_launch(void* const* d_in, const int* in_sizes, int n_in,
                              void* d_out, int out_size, void* d_ws, size_t ws_size,
                              hipStream_t stream) {
  const float* src   = (const float*)d_in[0];   // [B,T,D]
  const float* mb    = (const float*)d_in[1];   // [B,S,D]
  const float* probs = (const float*)d_in[2];   // [B,S]
  const int*   lens  = (const int*)d_in[3];     // [B]
  const float* Win   = (const float*)d_in[4];   // [D,D]
  const float* Wout  = (const float*)d_in[5];   // [D,2D]

  float* out  = (float*)d_out;
  float* out0 = out;                              // attn_h      [T,B,D]
  float* out1 = out + (size_t)Tn * Bn * Dn;       // align_vec   [T,B,S]
  float* out2 = out1 + (size_t)Tn * Bn * Sn;      // norescale   [T,B,S]

  // ws: q split (2 x 16.8 MB fp16), later overwritten by c (16.8 MB fp16).
  _Float16* qh = (_Float16*)d_ws;
  _Float16* ql = qh + (size_t)Bn * Tn * Dn;
  _Float16* cbuf = (_Float16*)d_ws;               // reuses q region after g2

  // 1) q = source @ W_in^T (split fp16 output)
  g1_k<<<dim3(Dn / 128, (Bn * Tn) / 64), 256, 0, stream>>>(src, Win, qh, ql);

  // 2) align[b] = q[b] @ mb[b]^T -> out1 [T][B][S]
  g2_k<<<dim3(Sn / 64, 1, Bn), 256, 0, stream>>>(qh, ql, mb, out1);

  // 3) masked softmax + rescale + renormalize
  softmax_k<<<Tn * Bn, 256, 0, stream>>>(out1, probs, lens, out2);

  // 4) c[b] = av[b] @ mb[b] -> fp16 (overwrites q region in ws)
  g4_k<<<dim3(Dn / 128, 1, Bn), 256, 0, stream>>>(out1, mb, cbuf);

  // 5) attn_h = tanh([c, src] @ W_out^T) -> out0 [T][B][D]
  g5_k<<<dim3(Dn / 128, (Bn * Tn) / 64), 256, 0, stream>>>(cbuf, src, Wout, out0);
}